// Round 1
// baseline (375.728 us; speedup 1.0000x reference)
//
#include <hip/hip_runtime.h>

// SpatialTransformer: 3D trilinear warp with dense displacement field.
// vol: [B,D,H,W,C] f32, trf: [B,D,H,W,3] f32 -> out: [B,D,H,W,C] f32
// B=2, D=H=W=160, C=2 (fixed by setup_inputs).

#define BLK 256
constexpr int Bn = 2, Dn = 160, Hn = 160, Wn = 160;
// C = 2 -> float2 per voxel.

__global__ __launch_bounds__(BLK) void st_warp_kernel(
    const float* __restrict__ vol,
    const float* __restrict__ trf,
    float* __restrict__ out)
{
    const int tid = threadIdx.x;
    const int gid = blockIdx.x * BLK + tid;   // voxel id, grid exactly covers B*D*H*W

    // ---- stage this block's trf slice through LDS (coalesced global reads) ----
    __shared__ float s_trf[BLK * 3];
    const int base = blockIdx.x * (BLK * 3);
    #pragma unroll
    for (int k = 0; k < 3; ++k)
        s_trf[k * BLK + tid] = trf[base + k * BLK + tid];
    __syncthreads();
    const float sd = s_trf[tid * 3 + 0];   // shift along D
    const float sh = s_trf[tid * 3 + 1];   // shift along H
    const float sw = s_trf[tid * 3 + 2];   // shift along W

    // ---- decompose voxel id ----
    int t = gid;
    const int w = t % Wn; t /= Wn;
    const int h = t % Hn; t /= Hn;
    const int d = t % Dn; t /= Dn;
    const int b = t;

    // ---- per-dim floor/ceil corners + weights (faithful to reference) ----
    // loc0c = clip(floor(loc),0,max); loc1c = clip(loc0c+1,0,max)
    // weight(floor corner) = loc1c - loc ; weight(ceil corner) = 1 - that.
    float loc, c0f, c1f;

    loc = (float)d + sd;
    c0f = fminf(fmaxf(floorf(loc), 0.0f), (float)(Dn - 1));
    c1f = fminf(c0f + 1.0f, (float)(Dn - 1));
    const float wd0 = c1f - loc, wd1 = 1.0f - wd0;
    const int id0 = (int)c0f, id1 = (int)c1f;

    loc = (float)h + sh;
    c0f = fminf(fmaxf(floorf(loc), 0.0f), (float)(Hn - 1));
    c1f = fminf(c0f + 1.0f, (float)(Hn - 1));
    const float wh0 = c1f - loc, wh1 = 1.0f - wh0;
    const int ih0 = (int)c0f, ih1 = (int)c1f;

    loc = (float)w + sw;
    c0f = fminf(fmaxf(floorf(loc), 0.0f), (float)(Wn - 1));
    c1f = fminf(c0f + 1.0f, (float)(Wn - 1));
    const float ww0 = c1f - loc, ww1 = 1.0f - ww0;
    const int iw0 = (int)c0f, iw1 = (int)c1f;

    // ---- 8 corner gathers (C=2 contiguous -> float2 loads) ----
    const float2* __restrict__ vol2 = (const float2*)vol;
    const int bo = b * Dn;
    const int rD0 = (bo + id0) * Hn;
    const int rD1 = (bo + id1) * Hn;
    const int r00 = (rD0 + ih0) * Wn;   // d0,h0
    const int r01 = (rD0 + ih1) * Wn;   // d0,h1
    const int r10 = (rD1 + ih0) * Wn;   // d1,h0
    const int r11 = (rD1 + ih1) * Wn;   // d1,h1

    float acc0 = 0.0f, acc1 = 0.0f;
    float2 v; float wt;
    // corner order matches itertools.product([0,1],repeat=3): (d,h,w) bits
    wt = wd0 * wh0 * ww0; v = vol2[r00 + iw0]; acc0 += wt * v.x; acc1 += wt * v.y; // 000
    wt = wd0 * wh0 * ww1; v = vol2[r00 + iw1]; acc0 += wt * v.x; acc1 += wt * v.y; // 001
    wt = wd0 * wh1 * ww0; v = vol2[r01 + iw0]; acc0 += wt * v.x; acc1 += wt * v.y; // 010
    wt = wd0 * wh1 * ww1; v = vol2[r01 + iw1]; acc0 += wt * v.x; acc1 += wt * v.y; // 011
    wt = wd1 * wh0 * ww0; v = vol2[r10 + iw0]; acc0 += wt * v.x; acc1 += wt * v.y; // 100
    wt = wd1 * wh0 * ww1; v = vol2[r10 + iw1]; acc0 += wt * v.x; acc1 += wt * v.y; // 101
    wt = wd1 * wh1 * ww0; v = vol2[r11 + iw0]; acc0 += wt * v.x; acc1 += wt * v.y; // 110
    wt = wd1 * wh1 * ww1; v = vol2[r11 + iw1]; acc0 += wt * v.x; acc1 += wt * v.y; // 111

    ((float2*)out)[gid] = make_float2(acc0, acc1);
}

extern "C" void kernel_launch(void* const* d_in, const int* in_sizes, int n_in,
                              void* d_out, int out_size, void* d_ws, size_t ws_size,
                              hipStream_t stream) {
    const float* vol = (const float*)d_in[0];
    const float* trf = (const float*)d_in[1];
    float* out = (float*)d_out;

    const int nvox = Bn * Dn * Hn * Wn;          // 8,192,000 — divisible by 256
    const int grid = nvox / BLK;                  // 32,000 blocks
    st_warp_kernel<<<grid, BLK, 0, stream>>>(vol, trf, out);
}

// Round 3
// 346.010 us; speedup vs baseline: 1.0859x; 1.0859x over previous
//
#include <hip/hip_runtime.h>

// SpatialTransformer: 3D trilinear warp with dense displacement field.
// vol: [B,D,H,W,C] f32, trf: [B,D,H,W,3] f32 -> out: [B,D,H,W,C] f32
// B=2, D=H=W=160, C=2 (fixed by setup_inputs).
//
// R3 = R2 with compile fix: __builtin_nontemporal_* requires a NATIVE vector
// type, not HIP_vector_type<float,2>. Use ext_vector_type(2).
//
// R2 design: blockIdx%8 selects an XCD (round-robin heuristic); each XCD owns
// one region = (batch, 40-row h-quarter) and sweeps d 0..159. Keeps each
// XCD's gather working set (~2.1 MB) inside its private 4 MB L2, cutting the
// 3.2x vol HBM over-fetch seen in R1. trf loads / out stores nontemporal so
// the streams don't evict vol lines from L2.

#define BLK 256
constexpr int Bn = 2, Dn = 160, Hn = 160, Wn = 160;
constexpr int HQ = 40;                 // h-quarter per region
constexpr int BLOCKS_PER_STRIP = (HQ * Wn) / BLK;   // 6400/256 = 25

typedef float f32x2 __attribute__((ext_vector_type(2)));

__global__ __launch_bounds__(BLK) void st_warp_kernel(
    const float* __restrict__ vol,
    const float* __restrict__ trf,
    float* __restrict__ out)
{
    const int tid = threadIdx.x;

    // ---- XCD-aware remap ----
    const int xcd = blockIdx.x & 7;          // assumed round-robin XCD assignment
    const int j   = blockIdx.x >> 3;         // 0..3999 sequential within an XCD
    const int b   = xcd >> 2;                // batch 0..1
    const int h0  = (xcd & 3) * HQ;          // h-quarter origin: 0,40,80,120
    const int d   = j / BLOCKS_PER_STRIP;    // d-plane 0..159 (slow sweep)
    const int r   = j % BLOCKS_PER_STRIP;    // strip-chunk 0..24
    const int p   = r * BLK + tid;           // 0..6399 within (40h x 160w) strip
    const int w   = p % Wn;
    const int h   = h0 + p / Wn;

    // global voxel id (matches [b,d,h,w] layout; writes stay contiguous per block)
    const int gvox = ((b * Dn + d) * Hn + h0) * Wn + p;

    // ---- stage this block's trf slice through LDS (coalesced, nontemporal) ----
    __shared__ float s_trf[BLK * 3];
    const long long tbase = (long long)(gvox - tid) * 3;
    #pragma unroll
    for (int k = 0; k < 3; ++k)
        s_trf[k * BLK + tid] = __builtin_nontemporal_load(&trf[tbase + k * BLK + tid]);
    __syncthreads();
    const float sd = s_trf[tid * 3 + 0];
    const float sh = s_trf[tid * 3 + 1];
    const float sw = s_trf[tid * 3 + 2];

    // ---- per-dim floor/ceil corners + weights (faithful to reference) ----
    float loc, c0f, c1f;

    loc = (float)d + sd;
    c0f = fminf(fmaxf(floorf(loc), 0.0f), (float)(Dn - 1));
    c1f = fminf(c0f + 1.0f, (float)(Dn - 1));
    const float wd0 = c1f - loc, wd1 = 1.0f - wd0;
    const int id0 = (int)c0f, id1 = (int)c1f;

    loc = (float)h + sh;
    c0f = fminf(fmaxf(floorf(loc), 0.0f), (float)(Hn - 1));
    c1f = fminf(c0f + 1.0f, (float)(Hn - 1));
    const float wh0 = c1f - loc, wh1 = 1.0f - wh0;
    const int ih0 = (int)c0f, ih1 = (int)c1f;

    loc = (float)w + sw;
    c0f = fminf(fmaxf(floorf(loc), 0.0f), (float)(Wn - 1));
    c1f = fminf(c0f + 1.0f, (float)(Wn - 1));
    const float ww0 = c1f - loc, ww1 = 1.0f - ww0;
    const int iw0 = (int)c0f, iw1 = (int)c1f;

    // ---- 8 corner gathers (C=2 contiguous -> float2 loads) ----
    const f32x2* __restrict__ vol2 = (const f32x2*)vol;
    const int bo  = b * Dn;
    const int rD0 = (bo + id0) * Hn;
    const int rD1 = (bo + id1) * Hn;
    const int r00 = (rD0 + ih0) * Wn;
    const int r01 = (rD0 + ih1) * Wn;
    const int r10 = (rD1 + ih0) * Wn;
    const int r11 = (rD1 + ih1) * Wn;

    float acc0 = 0.0f, acc1 = 0.0f;
    f32x2 v; float wt;
    wt = wd0 * wh0 * ww0; v = vol2[r00 + iw0]; acc0 += wt * v.x; acc1 += wt * v.y; // 000
    wt = wd0 * wh0 * ww1; v = vol2[r00 + iw1]; acc0 += wt * v.x; acc1 += wt * v.y; // 001
    wt = wd0 * wh1 * ww0; v = vol2[r01 + iw0]; acc0 += wt * v.x; acc1 += wt * v.y; // 010
    wt = wd0 * wh1 * ww1; v = vol2[r01 + iw1]; acc0 += wt * v.x; acc1 += wt * v.y; // 011
    wt = wd1 * wh0 * ww0; v = vol2[r10 + iw0]; acc0 += wt * v.x; acc1 += wt * v.y; // 100
    wt = wd1 * wh0 * ww1; v = vol2[r10 + iw1]; acc0 += wt * v.x; acc1 += wt * v.y; // 101
    wt = wd1 * wh1 * ww0; v = vol2[r11 + iw0]; acc0 += wt * v.x; acc1 += wt * v.y; // 110
    wt = wd1 * wh1 * ww1; v = vol2[r11 + iw1]; acc0 += wt * v.x; acc1 += wt * v.y; // 111

    // nontemporal store (write stream shouldn't pollute L2)
    f32x2 res; res.x = acc0; res.y = acc1;
    __builtin_nontemporal_store(res, &((f32x2*)out)[gvox]);
}

extern "C" void kernel_launch(void* const* d_in, const int* in_sizes, int n_in,
                              void* d_out, int out_size, void* d_ws, size_t ws_size,
                              hipStream_t stream) {
    const float* vol = (const float*)d_in[0];
    const float* trf = (const float*)d_in[1];
    float* out = (float*)d_out;

    const int nvox = Bn * Dn * Hn * Wn;   // 8,192,000
    const int grid = nvox / BLK;          // 32,000 blocks, %8 == 0
    st_warp_kernel<<<grid, BLK, 0, stream>>>(vol, trf, out);
}

// Round 4
// 335.336 us; speedup vs baseline: 1.1205x; 1.0318x over previous
//
#include <hip/hip_runtime.h>

// SpatialTransformer: 3D trilinear warp with dense displacement field.
// vol: [B,D,H,W,C] f32, trf: [B,D,H,W,3] f32 -> out: [B,D,H,W,C] f32
// B=2, D=H=W=160, C=2 (fixed by setup_inputs).
//
// R4: fuse w-corner pairs into one 16B dwordx4 gather per (d,h) row.
//   iw1 = min(iw0+1,159) -> both w-corners are adjacent float2s; load
//   f32x4 at m = min(iw0,158). Interior: corner0=.xy, corner1=.zw.
//   Boundary (iw0==159): corner0=.zw, corner1=.zw.  8 gathers -> 4.
//   (R1->R3 showed the kernel is TA/TCP transaction-bound: HBM 6%, VALU 10%,
//    occupancy 87% — nothing saturated except the gather pipe.)
// R2/R3 retained: XCD-region remap (blockIdx%8 -> batch x h-quarter, d-sweep)
//   keeps gather working set in per-XCD L2; nontemporal trf/out streams.

#define BLK 256
constexpr int Bn = 2, Dn = 160, Hn = 160, Wn = 160;
constexpr int HQ = 40;                 // h-quarter per region
constexpr int BLOCKS_PER_STRIP = (HQ * Wn) / BLK;   // 6400/256 = 25

typedef float f32x2 __attribute__((ext_vector_type(2)));
typedef float f32x4 __attribute__((ext_vector_type(4), aligned(8)));  // 8B-aligned 16B load

__global__ __launch_bounds__(BLK) void st_warp_kernel(
    const float* __restrict__ vol,
    const float* __restrict__ trf,
    float* __restrict__ out)
{
    const int tid = threadIdx.x;

    // ---- XCD-aware remap ----
    const int xcd = blockIdx.x & 7;          // assumed round-robin XCD assignment
    const int j   = blockIdx.x >> 3;         // 0..3999 sequential within an XCD
    const int b   = xcd >> 2;                // batch 0..1
    const int h0  = (xcd & 3) * HQ;          // h-quarter origin: 0,40,80,120
    const int d   = j / BLOCKS_PER_STRIP;    // d-plane 0..159 (slow sweep)
    const int r   = j % BLOCKS_PER_STRIP;    // strip-chunk 0..24
    const int p   = r * BLK + tid;           // 0..6399 within (40h x 160w) strip
    const int w   = p % Wn;
    const int h   = h0 + p / Wn;

    const int gvox = ((b * Dn + d) * Hn + h0) * Wn + p;

    // ---- stage this block's trf slice through LDS (coalesced, nontemporal) ----
    __shared__ float s_trf[BLK * 3];
    const long long tbase = (long long)(gvox - tid) * 3;
    #pragma unroll
    for (int k = 0; k < 3; ++k)
        s_trf[k * BLK + tid] = __builtin_nontemporal_load(&trf[tbase + k * BLK + tid]);
    __syncthreads();
    const float sd = s_trf[tid * 3 + 0];
    const float sh = s_trf[tid * 3 + 1];
    const float sw = s_trf[tid * 3 + 2];

    // ---- per-dim floor/ceil corners + weights (faithful to reference) ----
    float loc, c0f, c1f;

    loc = (float)d + sd;
    c0f = fminf(fmaxf(floorf(loc), 0.0f), (float)(Dn - 1));
    c1f = fminf(c0f + 1.0f, (float)(Dn - 1));
    const float wd0 = c1f - loc, wd1 = 1.0f - wd0;
    const int id0 = (int)c0f, id1 = (int)c1f;

    loc = (float)h + sh;
    c0f = fminf(fmaxf(floorf(loc), 0.0f), (float)(Hn - 1));
    c1f = fminf(c0f + 1.0f, (float)(Hn - 1));
    const float wh0 = c1f - loc, wh1 = 1.0f - wh0;
    const int ih0 = (int)c0f, ih1 = (int)c1f;

    loc = (float)w + sw;
    c0f = fminf(fmaxf(floorf(loc), 0.0f), (float)(Wn - 1));
    c1f = fminf(c0f + 1.0f, (float)(Wn - 1));
    const float ww0 = c1f - loc, ww1 = 1.0f - ww0;
    const int iw0 = (int)c0f;

    // ---- 4 fused row gathers (16B each: both w-corners x both channels) ----
    const int bo  = b * Dn;
    const int r00 = ((bo + id0) * Hn + ih0) * Wn;   // d0,h0
    const int r01 = ((bo + id0) * Hn + ih1) * Wn;   // d0,h1
    const int r10 = ((bo + id1) * Hn + ih0) * Wn;   // d1,h0
    const int r11 = ((bo + id1) * Hn + ih1) * Wn;   // d1,h1

    const bool lo = (iw0 < Wn - 1);
    const int  m  = lo ? iw0 : (Wn - 2);            // load start (float2 units)

    const f32x4 vA = *(const f32x4*)(vol + (((long long)(r00 + m)) << 1));
    const f32x4 vB = *(const f32x4*)(vol + (((long long)(r01 + m)) << 1));
    const f32x4 vC = *(const f32x4*)(vol + (((long long)(r10 + m)) << 1));
    const f32x4 vD = *(const f32x4*)(vol + (((long long)(r11 + m)) << 1));

    // corner0 = lo ? .xy : .zw ; corner1 = .zw always
    const float wA = wd0 * wh0, wB = wd0 * wh1, wC = wd1 * wh0, wD = wd1 * wh1;

    float a0x = lo ? vA.x : vA.z, a0y = lo ? vA.y : vA.w;
    float b0x = lo ? vB.x : vB.z, b0y = lo ? vB.y : vB.w;
    float c0x = lo ? vC.x : vC.z, c0y = lo ? vC.y : vC.w;
    float d0x = lo ? vD.x : vD.z, d0y = lo ? vD.y : vD.w;

    float acc0 = wA * (ww0 * a0x + ww1 * vA.z)
               + wB * (ww0 * b0x + ww1 * vB.z)
               + wC * (ww0 * c0x + ww1 * vC.z)
               + wD * (ww0 * d0x + ww1 * vD.z);
    float acc1 = wA * (ww0 * a0y + ww1 * vA.w)
               + wB * (ww0 * b0y + ww1 * vB.w)
               + wC * (ww0 * c0y + ww1 * vC.w)
               + wD * (ww0 * d0y + ww1 * vD.w);

    f32x2 res; res.x = acc0; res.y = acc1;
    __builtin_nontemporal_store(res, &((f32x2*)out)[gvox]);
}

extern "C" void kernel_launch(void* const* d_in, const int* in_sizes, int n_in,
                              void* d_out, int out_size, void* d_ws, size_t ws_size,
                              hipStream_t stream) {
    const float* vol = (const float*)d_in[0];
    const float* trf = (const float*)d_in[1];
    float* out = (float*)d_out;

    const int nvox = Bn * Dn * Hn * Wn;   // 8,192,000
    const int grid = nvox / BLK;          // 32,000 blocks, %8 == 0
    st_warp_kernel<<<grid, BLK, 0, stream>>>(vol, trf, out);
}

// Round 5
// 312.222 us; speedup vs baseline: 1.2034x; 1.0740x over previous
//
#include <hip/hip_runtime.h>

// SpatialTransformer: 3D trilinear warp with dense displacement field.
// vol: [B,D,H,W,C] f32, trf: [B,D,H,W,3] f32 -> out: [B,D,H,W,C] f32
// B=2, D=H=W=160, C=2 (fixed by setup_inputs).
//
// R5: latency/MLP attack. R1-R4 showed: HBM 10%, VALU 10%, 0 bank conflicts,
// occupancy 87%, and halving gather instructions moved nothing -> each wave
// stalls on vmcnt with only 4 loads in flight. Now each thread processes
// V=4 voxels: issue all 12 trf dwords, then all 16 fused gathers, then math.
// 16 loads in flight/wave; __launch_bounds__(256,4) caps VGPR at 128
// (4 waves/SIMD) -> per-SIMD MLP 28 -> 64.
//
// Retained: XCD-region remap (blockIdx%8 -> batch x 40-row h-quarter,
// d-major sweep) keeps gather working set in per-XCD L2 (FETCH 307->88 MB);
// nontemporal trf/out streams; fused w-corner 16B gathers (iw1=min(iw0+1,159)
// => both w-corners adjacent; boundary folded into weights: ww0->0, ww1->1,
// exact since ww0+ww1==1 when iw0==159).

#define BLK 256
constexpr int Bn = 2, Dn = 160, Hn = 160, Wn = 160;
constexpr int HQ = 40;                    // h-quarter rows per XCD region
constexpr int RSTRIP = HQ * Wn;           // 6400 voxels per (d, quarter) plane
constexpr int V = 4;                      // voxels per thread

typedef float f32x2 __attribute__((ext_vector_type(2)));
typedef float f32x4 __attribute__((ext_vector_type(4), aligned(8)));  // 8B-aligned 16B load

__global__ __launch_bounds__(BLK, 4) void st_warp_kernel(
    const float* __restrict__ vol,
    const float* __restrict__ trf,
    float* __restrict__ out)
{
    const int tid = threadIdx.x;
    const int xcd = blockIdx.x & 7;          // round-robin XCD heuristic
    const int j   = blockIdx.x >> 3;         // 0..999 within region
    const int b   = xcd >> 2;                // batch
    const int h0  = (xcd & 3) * HQ;          // h-quarter origin

    // ---- phase 0: voxel ids + all trf loads (12 dwords in flight) ----
    int   gvox[V];
    float sd[V], sh[V], sw[V];
    #pragma unroll
    for (int k = 0; k < V; ++k) {
        const int v   = j * (BLK * V) + k * BLK + tid;   // region-linear voxel
        const int d   = v / RSTRIP;
        const int rem = v - d * RSTRIP;
        const int hh  = rem / Wn;
        const int w   = rem - hh * Wn;
        gvox[k] = ((b * Dn + d) * Hn + (h0 + hh)) * Wn + w;
    }
    #pragma unroll
    for (int k = 0; k < V; ++k) {
        const float* tp = trf + (long long)gvox[k] * 3;
        sd[k] = __builtin_nontemporal_load(tp + 0);
        sh[k] = __builtin_nontemporal_load(tp + 1);
        sw[k] = __builtin_nontemporal_load(tp + 2);
    }

    // ---- phase 1: weights + issue all 16 fused gathers ----
    f32x4 val[4 * V];
    float wA[V], wB[V], wC[V], wD[V], w0[V], w1[V];
    #pragma unroll
    for (int k = 0; k < V; ++k) {
        const int v   = j * (BLK * V) + k * BLK + tid;
        const int d   = v / RSTRIP;
        const int rem = v - d * RSTRIP;
        const int hh  = rem / Wn;
        const int w   = rem - hh * Wn;
        const int h   = h0 + hh;

        float loc, c0f, c1f;

        loc = (float)d + sd[k];
        c0f = fminf(fmaxf(floorf(loc), 0.0f), (float)(Dn - 1));
        c1f = fminf(c0f + 1.0f, (float)(Dn - 1));
        const float wd0 = c1f - loc, wd1 = 1.0f - wd0;
        const int id0 = (int)c0f, id1 = (int)c1f;

        loc = (float)h + sh[k];
        c0f = fminf(fmaxf(floorf(loc), 0.0f), (float)(Hn - 1));
        c1f = fminf(c0f + 1.0f, (float)(Hn - 1));
        const float wh0 = c1f - loc, wh1 = 1.0f - wh0;
        const int ih0 = (int)c0f, ih1 = (int)c1f;

        loc = (float)w + sw[k];
        c0f = fminf(fmaxf(floorf(loc), 0.0f), (float)(Wn - 1));
        c1f = fminf(c0f + 1.0f, (float)(Wn - 1));
        const float ww0 = c1f - loc, ww1 = 1.0f - ww0;
        const int iw0 = (int)c0f;

        const bool lo = (iw0 < Wn - 1);
        const int  m  = lo ? iw0 : (Wn - 2);
        // boundary: corner0 weight -> 0, corner1 weight -> 1 (exact: ww0+ww1==1)
        w0[k] = lo ? ww0 : 0.0f;
        w1[k] = lo ? ww1 : 1.0f;
        wA[k] = wd0 * wh0; wB[k] = wd0 * wh1;
        wC[k] = wd1 * wh0; wD[k] = wd1 * wh1;

        const int bo  = b * Dn;
        const int r00 = ((bo + id0) * Hn + ih0) * Wn;
        const int r01 = ((bo + id0) * Hn + ih1) * Wn;
        const int r10 = ((bo + id1) * Hn + ih0) * Wn;
        const int r11 = ((bo + id1) * Hn + ih1) * Wn;

        val[4 * k + 0] = *(const f32x4*)(vol + (((long long)(r00 + m)) << 1));
        val[4 * k + 1] = *(const f32x4*)(vol + (((long long)(r01 + m)) << 1));
        val[4 * k + 2] = *(const f32x4*)(vol + (((long long)(r10 + m)) << 1));
        val[4 * k + 3] = *(const f32x4*)(vol + (((long long)(r11 + m)) << 1));
    }

    // ---- phase 2: combine + store ----
    #pragma unroll
    for (int k = 0; k < V; ++k) {
        const f32x4 vA = val[4 * k + 0], vB = val[4 * k + 1];
        const f32x4 vC = val[4 * k + 2], vD = val[4 * k + 3];
        const float acc0 = wA[k] * (w0[k] * vA.x + w1[k] * vA.z)
                         + wB[k] * (w0[k] * vB.x + w1[k] * vB.z)
                         + wC[k] * (w0[k] * vC.x + w1[k] * vC.z)
                         + wD[k] * (w0[k] * vD.x + w1[k] * vD.z);
        const float acc1 = wA[k] * (w0[k] * vA.y + w1[k] * vA.w)
                         + wB[k] * (w0[k] * vB.y + w1[k] * vB.w)
                         + wC[k] * (w0[k] * vC.y + w1[k] * vC.w)
                         + wD[k] * (w0[k] * vD.y + w1[k] * vD.w);
        f32x2 res; res.x = acc0; res.y = acc1;
        __builtin_nontemporal_store(res, &((f32x2*)out)[gvox[k]]);
    }
}

extern "C" void kernel_launch(void* const* d_in, const int* in_sizes, int n_in,
                              void* d_out, int out_size, void* d_ws, size_t ws_size,
                              hipStream_t stream) {
    const float* vol = (const float*)d_in[0];
    const float* trf = (const float*)d_in[1];
    float* out = (float*)d_out;

    const int nvox = Bn * Dn * Hn * Wn;       // 8,192,000
    const int grid = nvox / (BLK * V);        // 8000 blocks, %8 == 0
    st_warp_kernel<<<grid, BLK, 0, stream>>>(vol, trf, out);
}